// Round 1
// baseline (441.709 us; speedup 1.0000x reference)
//
#include <hip/hip_runtime.h>
#include <cstdint>
#include <cstddef>

// ---------------------------------------------------------------------------
// Problem constants
// ---------------------------------------------------------------------------
#define BB    8      // batch
#define NH    12     // heads
#define BH    96     // BB*NH
#define SS    1024   // image tokens (32x32)
#define QQ    2048   // text tokens
#define DD    64     // head dim
#define HID   768
#define EDGE  32
#define KPOOL 16
#define POOLED 17

typedef short bf16x8 __attribute__((ext_vector_type(8)));
typedef float f32x4  __attribute__((ext_vector_type(4)));

#define MFMA16(a, b, c) __builtin_amdgcn_mfma_f32_16x16x32_bf16((a), (b), (c), 0, 0, 0)

__device__ __forceinline__ short f2bf(float x) {
    unsigned u = __builtin_bit_cast(unsigned, x);
    u = u + 0x7fffu + ((u >> 16) & 1u);          // RNE
    return (short)(u >> 16);
}
__device__ __forceinline__ float bf2f(short h) {
    unsigned u = ((unsigned)(unsigned short)h) << 16;
    return __builtin_bit_cast(float, u);
}

// ---------------------------------------------------------------------------
// K0a: cast text -> Q split hi/lo bf16, layout [bh][q][hi 64 | lo 64]
// (pre-scaled by 1/8 = exact power of two, no extra rounding)
// ---------------------------------------------------------------------------
__global__ __launch_bounds__(256) void k_castq(const float* __restrict__ txt,
                                               short* __restrict__ Qs) {
    int t = threadIdx.x;
    int row = blockIdx.x * 4 + (t >> 6);         // row = bh*2048 + q
    int d = t & 63;
    int bh = row >> 11, q = row & 2047;
    int b = bh / NH, h = bh - b * NH;
    float x = txt[((size_t)b * QQ + q) * HID + h * DD + d] * 0.125f;
    short hi = f2bf(x);
    short lo = f2bf(x - bf2f(hi));
    size_t base = (size_t)row * 128;
    Qs[base + d] = hi;
    Qs[base + 64 + d] = lo;
}

// K0b: cast image -> K split hi/lo bf16, layout [bh][s][hi 64 | lo 64]
__global__ __launch_bounds__(256) void k_castk(const float* __restrict__ img,
                                               short* __restrict__ Ks) {
    int t = threadIdx.x;
    int row = blockIdx.x * 4 + (t >> 6);         // row = bh*1024 + s
    int d = t & 63;
    int bh = row >> 10, s = row & 1023;
    int b = bh / NH, h = bh - b * NH;
    float x = img[((size_t)b * SS + s) * HID + h * DD + d];
    short hi = f2bf(x);
    short lo = f2bf(x - bf2f(hi));
    size_t base = (size_t)row * 128;
    Ks[base + d] = hi;
    Ks[base + 64 + d] = lo;
}

// K0c: W_in [k][n] -> transposed bf16 [n][k] (B-operand contiguous in k)
__global__ __launch_bounds__(256) void k_castw(const float* __restrict__ W,
                                               short* __restrict__ Wt) {
    int n = blockIdx.x;
    for (int k = threadIdx.x; k < HID; k += 256)
        Wt[(size_t)n * HID + k] = f2bf(W[(size_t)k * HID + n]);
}

// ---------------------------------------------------------------------------
// K1: logL[bh][q] = log( sum_s exp(q.k/8) )   -- split-bf16 x3 MFMA
// grid: bh*8 q-blocks of 256; wave handles 64 q rows
// ---------------------------------------------------------------------------
__global__ __launch_bounds__(256) void k_logl(const short* __restrict__ Qs,
                                              const short* __restrict__ Ks,
                                              float* __restrict__ logL) {
    int bh = blockIdx.x >> 3;
    int qblk = blockIdx.x & 7;
    int wave = threadIdx.x >> 6, lane = threadIdx.x & 63;
    int quad = lane >> 4, c = lane & 15;
    int q0 = qblk * 256 + wave * 64;

    bf16x8 ahi0[4], ahi1[4], alo0[4], alo1[4];
#pragma unroll
    for (int t = 0; t < 4; t++) {
        const short* rp = Qs + ((size_t)bh * QQ + q0 + t * 16 + c) * 128 + quad * 8;
        ahi0[t] = *(const bf16x8*)(rp);
        ahi1[t] = *(const bf16x8*)(rp + 32);
        alo0[t] = *(const bf16x8*)(rp + 64);
        alo1[t] = *(const bf16x8*)(rp + 96);
    }
    f32x4 lacc[4];
#pragma unroll
    for (int t = 0; t < 4; t++) lacc[t] = (f32x4){0.f, 0.f, 0.f, 0.f};

    const short* kbase = Ks + (size_t)bh * SS * 128;
    for (int s0 = 0; s0 < SS; s0 += 16) {
        const short* rp = kbase + (size_t)(s0 + c) * 128 + quad * 8;
        bf16x8 bhi0 = *(const bf16x8*)(rp);
        bf16x8 bhi1 = *(const bf16x8*)(rp + 32);
        bf16x8 blo0 = *(const bf16x8*)(rp + 64);
        bf16x8 blo1 = *(const bf16x8*)(rp + 96);
#pragma unroll
        for (int t = 0; t < 4; t++) {
            f32x4 acc = (f32x4){0.f, 0.f, 0.f, 0.f};
            acc = MFMA16(ahi0[t], bhi0, acc);
            acc = MFMA16(ahi1[t], bhi1, acc);
            acc = MFMA16(alo0[t], bhi0, acc);
            acc = MFMA16(alo1[t], bhi1, acc);
            acc = MFMA16(ahi0[t], blo0, acc);
            acc = MFMA16(ahi1[t], blo1, acc);
#pragma unroll
            for (int r = 0; r < 4; r++) lacc[t][r] += __expf(acc[r]);
        }
    }
#pragma unroll
    for (int t = 0; t < 4; t++) {
#pragma unroll
        for (int r = 0; r < 4; r++) {
            float v = lacc[t][r];
            v += __shfl_xor(v, 1);
            v += __shfl_xor(v, 2);
            v += __shfl_xor(v, 4);
            v += __shfl_xor(v, 8);
            if (c == 0)
                logL[(size_t)bh * QQ + q0 + t * 16 + quad * 4 + r] = __logf(v);
        }
    }
}

// ---------------------------------------------------------------------------
// K2: image_attn[bh][s] += sum_q exp(score - logL[q])   (A = K, B = Q)
// grid: bh * 4 s-blocks * 2 q-halves; wave handles 64 s rows
// ---------------------------------------------------------------------------
__global__ __launch_bounds__(256) void k_attnacc(const short* __restrict__ Qs,
                                                 const short* __restrict__ Ks,
                                                 const float* __restrict__ logL,
                                                 float* __restrict__ iattn) {
    int idx = blockIdx.x;
    int qh = idx & 1;
    int sblk = (idx >> 1) & 3;
    int bh = idx >> 3;
    int wave = threadIdx.x >> 6, lane = threadIdx.x & 63;
    int quad = lane >> 4, c = lane & 15;
    int s0w = sblk * 256 + wave * 64;

    bf16x8 ahi0[4], ahi1[4], alo0[4], alo1[4];
#pragma unroll
    for (int t = 0; t < 4; t++) {
        const short* rp = Ks + ((size_t)bh * SS + s0w + t * 16 + c) * 128 + quad * 8;
        ahi0[t] = *(const bf16x8*)(rp);
        ahi1[t] = *(const bf16x8*)(rp + 32);
        alo0[t] = *(const bf16x8*)(rp + 64);
        alo1[t] = *(const bf16x8*)(rp + 96);
    }
    f32x4 racc[4];
#pragma unroll
    for (int t = 0; t < 4; t++) racc[t] = (f32x4){0.f, 0.f, 0.f, 0.f};

    const short* qbase = Qs + (size_t)bh * QQ * 128;
    const float* lbase = logL + (size_t)bh * QQ;
    int qstart = qh * 1024;
    for (int q0 = qstart; q0 < qstart + 1024; q0 += 16) {
        const short* rp = qbase + (size_t)(q0 + c) * 128 + quad * 8;
        bf16x8 bhi0 = *(const bf16x8*)(rp);
        bf16x8 bhi1 = *(const bf16x8*)(rp + 32);
        bf16x8 blo0 = *(const bf16x8*)(rp + 64);
        bf16x8 blo1 = *(const bf16x8*)(rp + 96);
        float lv = lbase[q0 + c];
#pragma unroll
        for (int t = 0; t < 4; t++) {
            f32x4 acc = (f32x4){0.f, 0.f, 0.f, 0.f};
            acc = MFMA16(ahi0[t], bhi0, acc);
            acc = MFMA16(ahi1[t], bhi1, acc);
            acc = MFMA16(alo0[t], bhi0, acc);
            acc = MFMA16(alo1[t], bhi1, acc);
            acc = MFMA16(ahi0[t], blo0, acc);
            acc = MFMA16(ahi1[t], blo1, acc);
#pragma unroll
            for (int r = 0; r < 4; r++) racc[t][r] += __expf(acc[r] - lv);
        }
    }
#pragma unroll
    for (int t = 0; t < 4; t++) {
#pragma unroll
        for (int r = 0; r < 4; r++) {
            float v = racc[t][r];
            v += __shfl_xor(v, 1);
            v += __shfl_xor(v, 2);
            v += __shfl_xor(v, 4);
            v += __shfl_xor(v, 8);
            if (c == 0)
                atomicAdd(&iattn[(size_t)bh * SS + s0w + t * 16 + quad * 4 + r], v);
        }
    }
}

// ---------------------------------------------------------------------------
// K3: 16x16 sum-pool (valid) over 32x32 map, argmax (np first-max tiebreak)
// ---------------------------------------------------------------------------
__global__ __launch_bounds__(256) void k_pool(const float* __restrict__ iattn,
                                              int* __restrict__ rc) {
    __shared__ float A[1024];
    __shared__ float V[POOLED * EDGE];
    __shared__ float bv[256];
    __shared__ int bi[256];
    int bh = blockIdx.x;
    for (int i = threadIdx.x; i < 1024; i += 256) A[i] = iattn[(size_t)bh * SS + i];
    __syncthreads();
    for (int i = threadIdx.x; i < POOLED * EDGE; i += 256) {
        int r = i >> 5, cc = i & 31;
        float s = 0.f;
#pragma unroll
        for (int k = 0; k < KPOOL; k++) s += A[(r + k) * EDGE + cc];
        V[i] = s;
    }
    __syncthreads();
    float best = -1e30f;
    int bidx = 1 << 30;
    for (int i = threadIdx.x; i < POOLED * POOLED; i += 256) {
        int r = i / POOLED, cc = i - r * POOLED;
        float s = 0.f;
#pragma unroll
        for (int k = 0; k < KPOOL; k++) s += V[r * EDGE + cc + k];
        if (s > best || (s == best && i < bidx)) { best = s; bidx = i; }
    }
    bv[threadIdx.x] = best;
    bi[threadIdx.x] = bidx;
    __syncthreads();
    for (int off = 128; off; off >>= 1) {
        if (threadIdx.x < off) {
            float ov = bv[threadIdx.x + off];
            int oi = bi[threadIdx.x + off];
            if (ov > bv[threadIdx.x] || (ov == bv[threadIdx.x] && oi < bi[threadIdx.x])) {
                bv[threadIdx.x] = ov;
                bi[threadIdx.x] = oi;
            }
        }
        __syncthreads();
    }
    if (threadIdx.x == 0) rc[bh] = bi[0];
}

// ---------------------------------------------------------------------------
// K4: gather region @ W_up, pixel-shuffle, write bf16 X [b][p2][h*64+d']
// grid: bh * 4 position-blocks (64 positions each); thread = one out channel
// ---------------------------------------------------------------------------
__global__ __launch_bounds__(256) void k_up(const float* __restrict__ img,
                                            const float* __restrict__ Wup,
                                            const int* __restrict__ rc,
                                            short* __restrict__ Xb) {
    __shared__ float R[64 * 64];
    int bh = blockIdx.x >> 2, pb = blockIdx.x & 3;
    int b = bh / NH, h = bh - b * NH;
    int idx = rc[bh];
    int r0 = idx / POOLED, c0 = idx - r0 * POOLED;

    for (int i = threadIdx.x; i < 4096; i += 256) {
        int pos = i >> 6, d = i & 63;
        int gi = r0 + pb * 4 + (pos >> 4);
        int gj = c0 + (pos & 15);
        R[i] = img[((size_t)b * SS + gi * EDGE + gj) * HID + h * DD + d];
    }
    __syncthreads();

    int oc = threadIdx.x;
    float w[64];
#pragma unroll
    for (int d = 0; d < 64; d++) w[d] = Wup[d * 256 + oc];
    int a = oc >> 7, bbit = (oc >> 6) & 1, dp = oc & 63;

    for (int pos = 0; pos < 64; pos++) {
        const float* rp = &R[pos * 64];
        float acc = 0.f;
#pragma unroll
        for (int d = 0; d < 64; d++) acc += rp[d] * w[d];
        int i16 = pb * 4 + (pos >> 4), j16 = pos & 15;
        int p2 = (2 * i16 + a) * EDGE + (2 * j16 + bbit);
        Xb[((size_t)b * SS + p2) * HID + h * DD + dp] = f2bf(acc);
    }
}

// ---------------------------------------------------------------------------
// K5: out = img + gelu(X @ W_in)   (bf16 MFMA, M=8192 N=768 K=768)
// grid: 32 m-blocks x 12 n-blocks; wave = 64m x 64n
// ---------------------------------------------------------------------------
__global__ __launch_bounds__(256) void k_out(const short* __restrict__ Xb,
                                             const short* __restrict__ Wt,
                                             const float* __restrict__ img,
                                             float* __restrict__ out) {
    int mblk = blockIdx.x & 31, nblk = blockIdx.x >> 5;
    int wave = threadIdx.x >> 6, lane = threadIdx.x & 63;
    int quad = lane >> 4, c = lane & 15;
    int m0 = mblk * 256 + wave * 64;
    int n0 = nblk * 64;

    f32x4 acc[4][4];
#pragma unroll
    for (int t = 0; t < 4; t++)
#pragma unroll
        for (int u = 0; u < 4; u++) acc[t][u] = (f32x4){0.f, 0.f, 0.f, 0.f};

    for (int k0 = 0; k0 < HID; k0 += 32) {
        bf16x8 a[4], bfr[4];
#pragma unroll
        for (int t = 0; t < 4; t++)
            a[t] = *(const bf16x8*)(Xb + (size_t)(m0 + t * 16 + c) * HID + k0 + quad * 8);
#pragma unroll
        for (int u = 0; u < 4; u++)
            bfr[u] = *(const bf16x8*)(Wt + (size_t)(n0 + u * 16 + c) * HID + k0 + quad * 8);
#pragma unroll
        for (int t = 0; t < 4; t++)
#pragma unroll
            for (int u = 0; u < 4; u++)
                acc[t][u] = MFMA16(a[t], bfr[u], acc[t][u]);
    }
#pragma unroll
    for (int t = 0; t < 4; t++) {
#pragma unroll
        for (int u = 0; u < 4; u++) {
#pragma unroll
            for (int r = 0; r < 4; r++) {
                int row = m0 + t * 16 + quad * 4 + r;
                int col = n0 + u * 16 + c;
                float x = acc[t][u][r];
                float g = 0.5f * x * (1.f + erff(x * 0.70710678118654752f));
                size_t o = (size_t)row * HID + col;
                out[o] = img[o] + g;
            }
        }
    }
}

// ---------------------------------------------------------------------------
// launch
// ---------------------------------------------------------------------------
extern "C" void kernel_launch(void* const* d_in, const int* in_sizes, int n_in,
                              void* d_out, int out_size, void* d_ws, size_t ws_size,
                              hipStream_t stream) {
    const float* img = (const float*)d_in[0];   // [8,1024,768]
    const float* txt = (const float*)d_in[1];   // [8,2048,768]
    const float* Win = (const float*)d_in[2];   // [768,768]
    const float* Wup = (const float*)d_in[3];   // [64,256]
    float* out = (float*)d_out;

    char* w = (char*)d_ws;
    short* Qs    = (short*)(w);                         // 96*2048*128*2 = 50331648
    short* Ks    = (short*)(w + 50331648);              // 96*1024*128*2 = 25165824
    short* Wt    = (short*)(w + 75497472);              // 768*768*2     = 1179648
    float* logL  = (float*)(w + 76677120);              // 96*2048*4     = 786432
    float* iattn = (float*)(w + 77463552);              // 96*1024*4     = 393216
    int*   rc    = (int*)(w + 77856768);                // 96*4
    short* Xb    = (short*)(w);                         // aliases Qs (dead after k_attnacc)

    k_castq<<<dim3(49152), dim3(256), 0, stream>>>(txt, Qs);
    k_castk<<<dim3(24576), dim3(256), 0, stream>>>(img, Ks);
    k_castw<<<dim3(768), dim3(256), 0, stream>>>(Win, Wt);
    k_logl<<<dim3(768), dim3(256), 0, stream>>>(Qs, Ks, logL);
    hipMemsetAsync(iattn, 0, (size_t)BH * SS * sizeof(float), stream);
    k_attnacc<<<dim3(768), dim3(256), 0, stream>>>(Qs, Ks, logL, iattn);
    k_pool<<<dim3(96), dim3(256), 0, stream>>>(iattn, rc);
    k_up<<<dim3(384), dim3(256), 0, stream>>>(img, Wup, rc, Xb);
    k_out<<<dim3(384), dim3(256), 0, stream>>>(Xb, Wt, img, out);
}